// Round 1
// baseline (191.716 us; speedup 1.0000x reference)
//
#include <hip/hip_runtime.h>

#define C8 8
#define LL 4
#define MM 8192
#define NGEN 16
#define NNODES 5461
#define NINT 1365
#define NLEAF 4096

// ---- workspace layout (float offsets) ----
#define WS_LOGDEN 0          // 128   [c*16+g]
#define WS_ASP    128        // 4096  [((i*8+k)*4+j)*16+g]
#define WS_LOGA   4224       // 4096
#define WS_SMPI   8320       // 512   [(c*4+j)*16+g]
#define WS_LOGPI  8832       // 512
#define WS_LOGSP  9344       // 64    [j*16+g]
#define WS_PART   9408       // 4096  bstat partials [(c*16+chunk)*16+g]*2
#define WS_BLEAF  13504      // 16*32768 = 524288  [g][p][c]
#define WS_TB     537792     // 64*10920 = 698880  per (b,g): [node][c]
#define WS_EPS    1236672    // 698880
// total 1935552 floats = 7.74 MB

// ---------------- K1: B row logsumexp partials + small-param softmaxes ----------------
__global__ void k_pre(const float* __restrict__ A, const float* __restrict__ B,
                      const float* __restrict__ Pi, const float* __restrict__ SP,
                      float* __restrict__ ws) {
    const int t = threadIdx.x;
    if (blockIdx.x < 128) {
        const int c = blockIdx.x >> 4, chunk = blockIdx.x & 15;
        const float* Bp = B + (size_t)c * (MM * NGEN) + (size_t)chunk * 8192;
        float mx = -3.4e38f, s = 0.f;
        for (int n = t; n < 8192; n += 256) {
            float v = Bp[n];
            float nm = fmaxf(mx, v);
            s = s * __expf(mx - nm) + __expf(v - nm);
            mx = nm;
        }
        __shared__ float sm[256], ss[256];
        sm[t] = mx; ss[t] = s;
        __syncthreads();
        for (int off = 128; off >= 16; off >>= 1) {
            if (t < off) {
                float m1 = sm[t], m2 = sm[t + off], s1 = ss[t], s2 = ss[t + off];
                float nm = fmaxf(m1, m2);
                sm[t] = nm;
                ss[t] = s1 * __expf(m1 - nm) + s2 * __expf(m2 - nm);
            }
            __syncthreads();
        }
        if (t < 16) {
            float* p = ws + WS_PART + (size_t)(((c * 16 + chunk) * 16 + t) * 2);
            p[0] = sm[t]; p[1] = ss[t];
        }
    } else {
        // params block
        __shared__ float s_smSP[64];
        if (t < 16) {
            int g = t;
            float v[4], mx = -3.4e38f;
            for (int j = 0; j < 4; j++) { v[j] = SP[j * 16 + g]; mx = fmaxf(mx, v[j]); }
            float s = 0.f;
            for (int j = 0; j < 4; j++) s += __expf(v[j] - mx);
            float ls = __logf(s);
            for (int j = 0; j < 4; j++) {
                s_smSP[j * 16 + g] = __expf(v[j] - mx) / s;
                ws[WS_LOGSP + j * 16 + g] = v[j] - mx - ls;
            }
        }
        if (t < 64) {
            int g = t & 15, j = t >> 4;
            float v[8], mx = -3.4e38f;
            for (int c = 0; c < 8; c++) { v[c] = Pi[(c * 4 + j) * 16 + g]; mx = fmaxf(mx, v[c]); }
            float s = 0.f;
            for (int c = 0; c < 8; c++) s += __expf(v[c] - mx);
            float ls = __logf(s);
            for (int c = 0; c < 8; c++) {
                int o = (c * 4 + j) * 16 + g;
                ws[WS_SMPI + o] = __expf(v[c] - mx) / s;
                ws[WS_LOGPI + o] = v[c] - mx - ls;
            }
        }
        __syncthreads();
        for (int grp = t; grp < 512; grp += 256) {
            int g = grp & 15, j = (grp >> 4) & 3, k = grp >> 6;
            float v[8], mx = -3.4e38f;
            for (int i = 0; i < 8; i++) { v[i] = A[((i * 8 + k) * 4 + j) * 16 + g]; mx = fmaxf(mx, v[i]); }
            float s = 0.f;
            for (int i = 0; i < 8; i++) s += __expf(v[i] - mx);
            float ls = __logf(s);
            float sp = s_smSP[j * 16 + g];
            for (int i = 0; i < 8; i++) {
                int o = ((i * 8 + k) * 4 + j) * 16 + g;
                ws[WS_ASP + o] = __expf(v[i] - mx) / s * sp;
                ws[WS_LOGA + o] = v[i] - mx - ls;
            }
        }
    }
}

// ---------------- K2: combine logsumexp partials ----------------
__global__ void k_comb(float* __restrict__ ws) {
    const int t = threadIdx.x; // 128 threads: (c,g)
    const int c = t >> 4, g = t & 15;
    float mx = -3.4e38f;
    for (int ch = 0; ch < 16; ch++)
        mx = fmaxf(mx, ws[WS_PART + ((c * 16 + ch) * 16 + g) * 2]);
    float s = 0.f;
    for (int ch = 0; ch < 16; ch++) {
        const float* p = ws + WS_PART + (size_t)(((c * 16 + ch) * 16 + g) * 2);
        s += p[1] * __expf(p[0] - mx);
    }
    ws[WS_LOGDEN + c * 16 + g] = mx + __logf(s);
}

// ---------------- K3: beta_leaf (batch-independent; uses leaf_idx per reference) ----------------
__global__ void k_leaf(const float* __restrict__ B, float* __restrict__ ws) {
    const int idx = blockIdx.x * 256 + threadIdx.x; // 65536 = 16g * 4096p
    const int g = idx >> 12, p = idx & 4095;
    const int pos = p & 3;
    float vals[8], s = 0.f;
    #pragma unroll
    for (int c = 0; c < 8; c++) {
        float ld = ws[WS_LOGDEN + c * 16 + g];
        float smpi = ws[WS_SMPI + (c * 4 + pos) * 16 + g];
        float v = smpi * __expf(B[((size_t)c * MM + 1365 + p) * 16 + g] - ld);
        vals[c] = v; s += v;
    }
    float inv = 1.0f / s;
    float* o = ws + WS_BLEAF + (size_t)g * 32768 + (size_t)p * 8;
    float4 v0 = make_float4(vals[0] * inv, vals[1] * inv, vals[2] * inv, vals[3] * inv);
    float4 v1 = make_float4(vals[4] * inv, vals[5] * inv, vals[6] * inv, vals[7] * inv);
    *(float4*)(o) = v0;
    *(float4*)(o + 4) = v1;
}

// ---------------- K4: per-(b,g) tree sweep ----------------
__global__ __launch_bounds__(256) void k_tree(const int* __restrict__ labels,
                                              const float* __restrict__ B,
                                              float* __restrict__ ws,
                                              float* __restrict__ out) {
    const int g = blockIdx.x;   // 0..15
    const int b = blockIdx.y;   // 0..3
    const int t = threadIdx.x;  // 256
    const int c8 = t & 7;       // i (upward) / k (downward)

    __shared__ __align__(16) float s_beta[NINT * 8]; // 10920 floats
    __shared__ float s_asp[256], s_loga[256], s_TS[256];
    __shared__ float s_logpi[32];
    __shared__ float s_logden[8];
    __shared__ float s_red[256];
    __shared__ float s_Alh[4];
    __shared__ float s_lh[2];

    s_asp[t] = ws[WS_ASP + t * 16 + g];
    s_loga[t] = ws[WS_LOGA + t * 16 + g];
    s_TS[t] = 0.f;
    if (t < 32) s_logpi[t] = ws[WS_LOGPI + t * 16 + g];
    if (t < 8)  s_logden[t] = ws[WS_LOGDEN + t * 16 + g];
    if (t < 4)  s_Alh[t] = 0.f;

    const float* bleaf = ws + WS_BLEAF + (size_t)g * 32768;
    float* tbet = ws + WS_TB + (size_t)(b * 16 + g) * (NINT * 8);
    float* epsb = ws + WS_EPS + (size_t)(b * 16 + g) * (NINT * 8);
    const int* lab = labels + (size_t)b * NNODES;
    __syncthreads();

    // hoist A_SP slices: aspU[k*4+j] = A_SP[i=c8,k,j]; aspD[i*4+j] = A_SP[i,k=c8,j]
    float aspU[32], aspD[32];
    #pragma unroll
    for (int k = 0; k < 8; k++)
        #pragma unroll
        for (int j = 0; j < 4; j++) {
            aspU[k * 4 + j] = s_asp[(c8 * 8 + k) * 4 + j];
            aspD[k * 4 + j] = s_asp[(k * 8 + c8) * 4 + j];
        }
    const float* Bi = B + (size_t)c8 * (MM * NGEN);
    const float ldc = s_logden[c8];

    // ---------- upward: d = 5..0 ----------
    #pragma unroll
    for (int d = 5; d >= 0; d--) {
        const int nd = 1 << (2 * d);
        const int start = ((1 << (2 * d)) - 1) / 3;
        const int start4 = start * 4 + 1;
        for (int idx = t; idx < nd * 8; idx += 256) {
            const int p = idx >> 3; // i == c8
            float tt = 0.f;
            if (d == 5) {
                const float* bp = bleaf + (size_t)(p * 4) * 8;
                #pragma unroll
                for (int j = 0; j < 4; j++) {
                    float4 lo = *(const float4*)(bp + j * 8);
                    float4 hi = *(const float4*)(bp + j * 8 + 4);
                    tt += aspU[0 + j] * lo.x + aspU[4 + j] * lo.y + aspU[8 + j] * lo.z + aspU[12 + j] * lo.w
                        + aspU[16 + j] * hi.x + aspU[20 + j] * hi.y + aspU[24 + j] * hi.z + aspU[28 + j] * hi.w;
                }
            } else {
                const float* bp = s_beta + (size_t)(start4 + p * 4) * 8;
                #pragma unroll
                for (int j = 0; j < 4; j++) {
                    float4 lo = *(const float4*)(bp + j * 8);
                    float4 hi = *(const float4*)(bp + j * 8 + 4);
                    tt += aspU[0 + j] * lo.x + aspU[4 + j] * lo.y + aspU[8 + j] * lo.z + aspU[12 + j] * lo.w
                        + aspU[16 + j] * hi.x + aspU[20 + j] * hi.y + aspU[24 + j] * hi.z + aspU[28 + j] * hi.w;
                }
            }
            const int node = start + p;
            const int lv = lab[node];
            const float bd = __expf(Bi[(size_t)lv * 16 + g] - ldc);
            const float bu = tt * bd;
            float ssum = bu;
            ssum += __shfl_xor(ssum, 1);
            ssum += __shfl_xor(ssum, 2);
            ssum += __shfl_xor(ssum, 4);
            s_beta[node * 8 + c8] = bu / ssum;
            tbet[node * 8 + c8] = tt;
        }
        __syncthreads();
    }

    // eps_0 = beta_0
    if (t < 8) epsb[t] = s_beta[t];
    __syncthreads();

    float pB = 0.f, pPi = 0.f;
    float Sacc[32];
    #pragma unroll
    for (int z = 0; z < 32; z++) Sacc[z] = 0.f;

    // ---------- downward: d = 0..5 ----------
    #pragma unroll
    for (int d = 0; d <= 5; d++) {
        const int nd = 1 << (2 * d);
        const int start = ((1 << (2 * d)) - 1) / 3;
        const int start4 = start * 4 + 1;
        // phase A: B_lhood for level d; overwrite eps <- r = eps / t_beta
        for (int idx = t; idx < nd * 8; idx += 256) {
            const int p = idx >> 3;
            const int node = start + p;
            const float ev = epsb[node * 8 + c8];
            const int lv = lab[node];
            pB += ev * (Bi[(size_t)lv * 16 + g] - ldc);
            epsb[node * 8 + c8] = ev / tbet[node * 8 + c8];
        }
        __syncthreads();
        // phase B+C: children eps, S accumulation, leaf likelihoods
        for (int idx = t; idx < nd * 8; idx += 256) {
            const int p = idx >> 3; // k == c8
            const int node = start + p;
            const float4 r0 = *(const float4*)(epsb + node * 8);
            const float4 r1 = *(const float4*)(epsb + node * 8 + 4);
            const float r8[8] = {r0.x, r0.y, r0.z, r0.w, r1.x, r1.y, r1.z, r1.w};
            float u[4] = {0.f, 0.f, 0.f, 0.f};
            #pragma unroll
            for (int i = 0; i < 8; i++) {
                u[0] += aspD[i * 4 + 0] * r8[i];
                u[1] += aspD[i * 4 + 1] * r8[i];
                u[2] += aspD[i * 4 + 2] * r8[i];
                u[3] += aspD[i * 4 + 3] * r8[i];
            }
            if (d < 5) {
                #pragma unroll
                for (int j = 0; j < 4; j++) {
                    const int child = start4 + p * 4 + j;
                    const float bc = s_beta[child * 8 + c8];
                    epsb[child * 8 + c8] = bc * u[j];
                    #pragma unroll
                    for (int i = 0; i < 8; i++) Sacc[i * 4 + j] += r8[i] * bc;
                }
            } else {
                #pragma unroll
                for (int j = 0; j < 4; j++) {
                    const int lp = p * 4 + j;
                    const float bc = bleaf[(size_t)lp * 8 + c8];
                    const float e6 = bc * u[j];
                    const int lv = lab[1365 + lp];
                    pB += e6 * (Bi[(size_t)lv * 16 + g] - ldc);
                    pPi += e6 * s_logpi[c8 * 4 + (lp & 3)];
                    #pragma unroll
                    for (int i = 0; i < 8; i++) Sacc[i * 4 + j] += r8[i] * bc;
                }
            }
        }
        __syncthreads();
    }

    // fold Sacc into s_TS (thread owns k=c8; 8 threads share each (i,k,j) -> atomics)
    #pragma unroll
    for (int i = 0; i < 8; i++)
        #pragma unroll
        for (int j = 0; j < 4; j++)
            atomicAdd(&s_TS[(i * 8 + c8) * 4 + j], Sacc[i * 4 + j]);

    // reduce pB
    s_red[t] = pB;
    __syncthreads();
    for (int off = 128; off >= 1; off >>= 1) {
        if (t < off) s_red[t] += s_red[t + off];
        __syncthreads();
    }
    if (t == 0) s_lh[0] = s_red[0];
    __syncthreads();
    // reduce pPi
    s_red[t] = pPi;
    __syncthreads();
    for (int off = 128; off >= 1; off >>= 1) {
        if (t < off) s_red[t] += s_red[t + off];
        __syncthreads();
    }
    if (t == 0) s_lh[1] = s_red[0];
    __syncthreads();

    // T_acc = A_SP * S ; A_lhood[j] = sum_{i,k} T_acc*log_smA
    const float val = s_asp[t] * s_TS[t];
    atomicAdd(&s_Alh[t & 3], val * s_loga[t]);
    __syncthreads();
    const int j = t & 3;
    const float res = -(s_Alh[j] + s_lh[0] + s_lh[1] + val * ws[WS_LOGSP + j * 16 + g]);
    out[(size_t)b * 4096 + t * 16 + g] = res;
}

extern "C" void kernel_launch(void* const* d_in, const int* in_sizes, int n_in,
                              void* d_out, int out_size, void* d_ws, size_t ws_size,
                              hipStream_t stream) {
    (void)in_sizes; (void)n_in; (void)out_size; (void)ws_size;
    const int* labels = (const int*)d_in[0];
    const float* A = (const float*)d_in[1];
    const float* B = (const float*)d_in[2];
    const float* Pi = (const float*)d_in[3];
    const float* SP = (const float*)d_in[4];
    float* ws = (float*)d_ws;
    float* out = (float*)d_out;

    hipLaunchKernelGGL(k_pre,  dim3(129), dim3(256), 0, stream, A, B, Pi, SP, ws);
    hipLaunchKernelGGL(k_comb, dim3(1),   dim3(128), 0, stream, ws);
    hipLaunchKernelGGL(k_leaf, dim3(256), dim3(256), 0, stream, B, ws);
    hipLaunchKernelGGL(k_tree, dim3(16, 4), dim3(256), 0, stream, labels, B, ws, out);
}

// Round 2
// 132.602 us; speedup vs baseline: 1.4458x; 1.4458x over previous
//
#include <hip/hip_runtime.h>

// C=8, L=4, M=8192, NGEN=16, DEPTH=6, BATCH=4, N=5461 (internal 1365, leaves 4096)
// Level starts: 0,1,5,21,85,341,1365,5461

// ---- workspace layout (float offsets) ----
#define WS_ASP    0          // 4096  [((i*8+k)*4+j)*16+g]
#define WS_LOGA   4096       // 4096
#define WS_SMPI   8192       // 512   [(c*4+j)*16+g]
#define WS_LOGPI  8704       // 512
#define WS_LOGSP  9216       // 64    [j*16+g]
#define WS_PART   9280       // 4096  logsumexp partials [(c*16+chunk)*16+g]*{max,sum}
#define WS_BLEAF  13376      // 524288  [g][p][c]
#define WS_Q5     537664     // 524288  per (b,g): [p][c]  (beta5/tt5)
#define WS_LOGBG  1061952    // 2796032 [b][g][node][c] = logB(label) - logden
// end 3857984 floats = 15.4 MB

// ---------------- K1: B row logsumexp partials + small-param softmaxes ----------------
__global__ void k_pre(const float* __restrict__ A, const float* __restrict__ B,
                      const float* __restrict__ Pi, const float* __restrict__ SP,
                      float* __restrict__ ws) {
    const int t = threadIdx.x;
    if (blockIdx.x < 128) {
        const int c = blockIdx.x >> 4, chunk = blockIdx.x & 15;
        const float* Bp = B + (size_t)c * (8192 * 16) + (size_t)chunk * 8192;
        float mx = -3.4e38f, s = 0.f;
        for (int n = t; n < 8192; n += 256) {
            float v = Bp[n];
            float nm = fmaxf(mx, v);
            s = s * __expf(mx - nm) + __expf(v - nm);
            mx = nm;
        }
        __shared__ float sm[256], ss[256];
        sm[t] = mx; ss[t] = s;
        __syncthreads();
        for (int off = 128; off >= 16; off >>= 1) {
            if (t < off) {
                float m1 = sm[t], m2 = sm[t + off], s1 = ss[t], s2 = ss[t + off];
                float nm = fmaxf(m1, m2);
                sm[t] = nm;
                ss[t] = s1 * __expf(m1 - nm) + s2 * __expf(m2 - nm);
            }
            __syncthreads();
        }
        if (t < 16) {
            float* p = ws + WS_PART + (size_t)(((c * 16 + chunk) * 16 + t) * 2);
            p[0] = sm[t]; p[1] = ss[t];
        }
    } else {
        __shared__ float s_smSP[64];
        if (t < 16) {
            int g = t;
            float v[4], mx = -3.4e38f;
            for (int j = 0; j < 4; j++) { v[j] = SP[j * 16 + g]; mx = fmaxf(mx, v[j]); }
            float s = 0.f;
            for (int j = 0; j < 4; j++) s += __expf(v[j] - mx);
            float ls = __logf(s);
            for (int j = 0; j < 4; j++) {
                s_smSP[j * 16 + g] = __expf(v[j] - mx) / s;
                ws[WS_LOGSP + j * 16 + g] = v[j] - mx - ls;
            }
        }
        if (t < 64) {
            int g = t & 15, j = t >> 4;
            float v[8], mx = -3.4e38f;
            for (int c = 0; c < 8; c++) { v[c] = Pi[(c * 4 + j) * 16 + g]; mx = fmaxf(mx, v[c]); }
            float s = 0.f;
            for (int c = 0; c < 8; c++) s += __expf(v[c] - mx);
            float ls = __logf(s);
            for (int c = 0; c < 8; c++) {
                int o = (c * 4 + j) * 16 + g;
                ws[WS_SMPI + o] = __expf(v[c] - mx) / s;
                ws[WS_LOGPI + o] = v[c] - mx - ls;
            }
        }
        __syncthreads();
        for (int grp = t; grp < 512; grp += 256) {
            int g = grp & 15, j = (grp >> 4) & 3, k = grp >> 6;
            float v[8], mx = -3.4e38f;
            for (int i = 0; i < 8; i++) { v[i] = A[((i * 8 + k) * 4 + j) * 16 + g]; mx = fmaxf(mx, v[i]); }
            float s = 0.f;
            for (int i = 0; i < 8; i++) s += __expf(v[i] - mx);
            float ls = __logf(s);
            float sp = s_smSP[j * 16 + g];
            for (int i = 0; i < 8; i++) {
                int o = ((i * 8 + k) * 4 + j) * 16 + g;
                ws[WS_ASP + o] = __expf(v[i] - mx) / s * sp;
                ws[WS_LOGA + o] = v[i] - mx - ls;
            }
        }
    }
}

// ---------------- K2 (fused): beta_leaf + logB gather; logden recomputed per block ----------------
__global__ void k_mid(const int* __restrict__ labels, const float* __restrict__ B,
                      float* __restrict__ ws) {
    __shared__ float s_ld[128];
    const int t = threadIdx.x;
    if (t < 128) {
        const int c = t >> 4, g = t & 15;
        float mx = -3.4e38f;
        for (int ch = 0; ch < 16; ch++)
            mx = fmaxf(mx, ws[WS_PART + ((c * 16 + ch) * 16 + g) * 2]);
        float s = 0.f;
        for (int ch = 0; ch < 16; ch++) {
            const float* p = ws + WS_PART + (size_t)(((c * 16 + ch) * 16 + g) * 2);
            s += p[1] * __expf(p[0] - mx);
        }
        s_ld[t] = mx + __logf(s);
    }
    __syncthreads();
    if (blockIdx.x < 256) {
        // beta_leaf: g-fast mapping for coalesced B reads
        const int id = blockIdx.x * 256 + t;     // 65536 = 4096p * 16g
        const int g = id & 15, p = id >> 4;
        const int pos = p & 3;
        float vals[8], ssum = 0.f;
        #pragma unroll
        for (int c = 0; c < 8; c++) {
            const float smpi = ws[WS_SMPI + (c * 4 + pos) * 16 + g];
            const float v = smpi * __expf(B[((size_t)(c * 8192) + 1365 + p) * 16 + g] - s_ld[c * 16 + g]);
            vals[c] = v; ssum += v;
        }
        const float inv = 1.0f / ssum;
        float* o = ws + WS_BLEAF + (size_t)g * 32768 + (size_t)p * 8;
        *(float4*)o       = make_float4(vals[0] * inv, vals[1] * inv, vals[2] * inv, vals[3] * inv);
        *(float4*)(o + 4) = make_float4(vals[4] * inv, vals[5] * inv, vals[6] * inv, vals[7] * inv);
    } else {
        // gather: one thread per (b,node,c), read full 64B B-line (16 g), write [b][g][node][c]
        const int item = (blockIdx.x - 256) * 256 + t;   // 174752 = 4b * 5461node * 8c
        if (item < 174752) {
            const int b = item / 43688;
            const int rem = item - b * 43688;
            const int node = rem >> 3, c = rem & 7;
            const int lv = labels[b * 5461 + node];
            const float* bp = B + ((size_t)(c * 8192) + lv) * 16;
            const float4 q0 = *(const float4*)bp;
            const float4 q1 = *(const float4*)(bp + 4);
            const float4 q2 = *(const float4*)(bp + 8);
            const float4 q3 = *(const float4*)(bp + 12);
            const float vg[16] = {q0.x,q0.y,q0.z,q0.w, q1.x,q1.y,q1.z,q1.w,
                                  q2.x,q2.y,q2.z,q2.w, q3.x,q3.y,q3.z,q3.w};
            float* dst = ws + WS_LOGBG + (size_t)b * (16 * 43688) + (size_t)node * 8 + c;
            #pragma unroll
            for (int g = 0; g < 16; g++)
                dst[(size_t)g * 43688] = vg[g] - s_ld[c * 16 + g];
        }
    }
}

// ---------------- K3: per-(b,g) tree sweep, 1024 threads, all-LDS state ----------------
__global__ __launch_bounds__(1024) void k_tree(float* __restrict__ ws,
                                               float* __restrict__ out) {
    const int g = blockIdx.x;   // 0..15
    const int b = blockIdx.y;   // 0..3
    const int t = threadIdx.x;  // 0..1023
    const int c8 = t & 7;
    const int pslot = t >> 3;   // 0..127

    // 65,504 B total LDS
    __shared__ __align__(16) float s_beta[2728]; // beta, levels 0..4 (node ids 0..340)
    __shared__ __align__(16) float s_q[2728];    // beta/tt, levels 0..4 (epilogue scratch later)
    __shared__ __align__(16) float s_r[2728];    // r = eps/t_beta, levels 1..4
    __shared__ __align__(16) float s_R[8192];    // beta5 (up) -> r5 (down) overlay; epilogue S staging

    const float* lgb = ws + WS_LOGBG + (size_t)(b * 16 + g) * 43688; // [node][c]
    const float* blf = ws + WS_BLEAF + (size_t)g * 32768;            // [p][c]
    float* q5g       = ws + WS_Q5 + (size_t)(b * 16 + g) * 8192;

    // A_SP slice for up-sweep: aspU[k*4+j] = A_SP[i=c8,k,j]
    float asp32[32];
    #pragma unroll
    for (int k = 0; k < 8; k++)
        #pragma unroll
        for (int j = 0; j < 4; j++)
            asp32[k * 4 + j] = ws[WS_ASP + ((c8 * 8 + k) * 4 + j) * 16 + g];

    // ---------- upward d=5 (children = leaves from blf) ----------
    #pragma unroll
    for (int it = 0; it < 8; ++it) {
        const int p = pslot + it * 128;          // level-5 local node
        const float* bp = blf + (size_t)p * 32;
        float tt = 0.f;
        #pragma unroll
        for (int j = 0; j < 4; j++) {
            float4 lo = *(const float4*)(bp + j * 8);
            float4 hi = *(const float4*)(bp + j * 8 + 4);
            tt += asp32[0 + j] * lo.x + asp32[4 + j] * lo.y + asp32[8 + j] * lo.z + asp32[12 + j] * lo.w
                + asp32[16 + j] * hi.x + asp32[20 + j] * hi.y + asp32[24 + j] * hi.z + asp32[28 + j] * hi.w;
        }
        const float e = __expf(lgb[(341 + p) * 8 + c8]);
        const float bu = tt * e;
        float ssum = bu;
        ssum += __shfl_xor(ssum, 1);
        ssum += __shfl_xor(ssum, 2);
        ssum += __shfl_xor(ssum, 4);
        const float beta = bu / ssum;
        s_R[p * 8 + c8] = beta;        // beta5 in LDS
        q5g[p * 8 + c8] = beta / tt;   // q5 to global (LDS budget)
    }
    __syncthreads();

    // ---------- upward d=4..0 ----------
    #pragma unroll
    for (int d = 4; d >= 0; --d) {
        const int nd = 1 << (2 * d);
        const int start = ((1 << (2 * d)) - 1) / 3;
        for (int idx = t; idx < nd * 8; idx += 1024) {
            const int p = idx >> 3;
            const float* bp = (d == 4) ? (s_R + (size_t)p * 32)
                                       : (s_beta + (size_t)(start * 4 + 1 + p * 4) * 8);
            float tt = 0.f;
            #pragma unroll
            for (int j = 0; j < 4; j++) {
                float4 lo = *(const float4*)(bp + j * 8);
                float4 hi = *(const float4*)(bp + j * 8 + 4);
                tt += asp32[0 + j] * lo.x + asp32[4 + j] * lo.y + asp32[8 + j] * lo.z + asp32[12 + j] * lo.w
                    + asp32[16 + j] * hi.x + asp32[20 + j] * hi.y + asp32[24 + j] * hi.z + asp32[28 + j] * hi.w;
            }
            const int node = start + p;
            const float e = __expf(lgb[node * 8 + c8]);
            const float bu = tt * e;
            float ssum = bu;
            ssum += __shfl_xor(ssum, 1);
            ssum += __shfl_xor(ssum, 2);
            ssum += __shfl_xor(ssum, 4);
            const float beta = bu / ssum;
            s_beta[node * 8 + c8] = beta;
            s_q[node * 8 + c8] = beta / tt;
        }
        __syncthreads();
    }

    // ---------- downward ----------
    float Sacc[32];
    #pragma unroll
    for (int z = 0; z < 32; z++) Sacc[z] = 0.f;
    // reload as aspD[i*4+j] = A_SP[i,k=c8,j]
    #pragma unroll
    for (int i = 0; i < 8; i++)
        #pragma unroll
        for (int j = 0; j < 4; j++)
            asp32[i * 4 + j] = ws[WS_ASP + ((i * 8 + c8) * 4 + j) * 16 + g];
    float lpi[4];
    #pragma unroll
    for (int j = 0; j < 4; j++) lpi[j] = ws[WS_LOGPI + (c8 * 4 + j) * 16 + g];

    // level-0: eps_0 = beta_0; r_0 = q_0 (read in pass 0 directly from s_q)
    float pB = (t < 8) ? s_beta[t] * lgb[t] : 0.f;
    float pPi = 0.f;

    #pragma unroll
    for (int d = 0; d <= 5; ++d) {
        const int nd = 1 << (2 * d);
        const int start = ((1 << (2 * d)) - 1) / 3;
        const int start4 = start * 4 + 1;
        for (int idx = t; idx < nd * 8; idx += 1024) {
            const int p = idx >> 3;
            const float* rp = (d == 0) ? s_q
                            : (d == 5) ? (s_R + (size_t)p * 8)
                                       : (s_r + (size_t)(start + p) * 8);
            const float4 r0 = *(const float4*)rp;
            const float4 r1 = *(const float4*)(rp + 4);
            const float r8[8] = {r0.x, r0.y, r0.z, r0.w, r1.x, r1.y, r1.z, r1.w};
            float u[4] = {0.f, 0.f, 0.f, 0.f};
            #pragma unroll
            for (int i = 0; i < 8; i++) {
                u[0] += asp32[i * 4 + 0] * r8[i];
                u[1] += asp32[i * 4 + 1] * r8[i];
                u[2] += asp32[i * 4 + 2] * r8[i];
                u[3] += asp32[i * 4 + 3] * r8[i];
            }
            if (d <= 3) {
                #pragma unroll
                for (int j = 0; j < 4; j++) {
                    const int ch = start4 + p * 4 + j;        // levels 1..4
                    const float bc = s_beta[ch * 8 + c8];
                    pB += bc * u[j] * lgb[ch * 8 + c8];
                    s_r[ch * 8 + c8] = s_q[ch * 8 + c8] * u[j];
                    #pragma unroll
                    for (int i = 0; i < 8; i++) Sacc[i * 4 + j] += r8[i] * bc;
                }
            } else if (d == 4) {
                #pragma unroll
                for (int j = 0; j < 4; j++) {
                    const int cl = p * 4 + j;                 // level-5 local
                    const float bc = s_R[cl * 8 + c8];        // beta5 (read before overlay write)
                    pB += bc * u[j] * lgb[(341 + cl) * 8 + c8];
                    s_R[cl * 8 + c8] = q5g[cl * 8 + c8] * u[j]; // r5 overlays beta5 (same thread)
                    #pragma unroll
                    for (int i = 0; i < 8; i++) Sacc[i * 4 + j] += r8[i] * bc;
                }
            } else {
                #pragma unroll
                for (int j = 0; j < 4; j++) {
                    const int lp = p * 4 + j;                 // leaf local
                    const float bc = blf[(size_t)lp * 8 + c8];
                    const float e6 = bc * u[j];
                    pB += e6 * lgb[(1365 + lp) * 8 + c8];
                    pPi += e6 * lpi[j];
                    #pragma unroll
                    for (int i = 0; i < 8; i++) Sacc[i * 4 + j] += r8[i] * bc;
                }
            }
        }
        __syncthreads();
    }

    // ---------- epilogue: reductions ----------
    // S: reduce over pslots within each wave (lanes xor 8,16,32), stage per-wave, then fold
    #pragma unroll
    for (int z = 0; z < 32; z++) {
        float v = Sacc[z];
        v += __shfl_xor(v, 8);
        v += __shfl_xor(v, 16);
        v += __shfl_xor(v, 32);
        Sacc[z] = v;
    }
    #pragma unroll
    for (int m = 1; m < 64; m <<= 1) { pB += __shfl_xor(pB, m); pPi += __shfl_xor(pPi, m); }

    const int lane = t & 63, wv = t >> 6;
    float* s_wp  = s_q;        // epilogue scratch aliases s_q (dead after pass 3)
    float* s_wq  = s_q + 16;
    float* s_Alh = s_q + 32;
    float* s_lh  = s_q + 40;
    if (lane < 8) {
        #pragma unroll
        for (int z = 0; z < 32; z++)   // index (i*8+c8)*4+j with i=z>>2, j=z&3, c8=lane
            s_R[wv * 256 + ((z >> 2) * 8 + lane) * 4 + (z & 3)] = Sacc[z];
    }
    if (lane == 0) { s_wp[wv] = pB; s_wq[wv] = pPi; }
    if (t < 4) s_Alh[t] = 0.f;
    __syncthreads();
    float val = 0.f;
    if (t < 256) {
        float TS = 0.f;
        #pragma unroll
        for (int w = 0; w < 16; w++) TS += s_R[w * 256 + t];
        const float asp = ws[WS_ASP + t * 16 + g];
        const float lga = ws[WS_LOGA + t * 16 + g];
        val = asp * TS;                          // T_acc element
        atomicAdd(&s_Alh[t & 3], val * lga);
    }
    if (t == 0) {
        float a = 0.f, c = 0.f;
        #pragma unroll
        for (int w = 0; w < 16; w++) { a += s_wp[w]; c += s_wq[w]; }
        s_lh[0] = a; s_lh[1] = c;
    }
    __syncthreads();
    if (t < 256) {
        const float res = -(s_Alh[t & 3] + s_lh[0] + s_lh[1] + val * ws[WS_LOGSP + (t & 3) * 16 + g]);
        out[(size_t)b * 4096 + t * 16 + g] = res;
    }
}

extern "C" void kernel_launch(void* const* d_in, const int* in_sizes, int n_in,
                              void* d_out, int out_size, void* d_ws, size_t ws_size,
                              hipStream_t stream) {
    (void)in_sizes; (void)n_in; (void)out_size; (void)ws_size;
    const int* labels = (const int*)d_in[0];
    const float* A  = (const float*)d_in[1];
    const float* B  = (const float*)d_in[2];
    const float* Pi = (const float*)d_in[3];
    const float* SP = (const float*)d_in[4];
    float* ws = (float*)d_ws;
    float* out = (float*)d_out;

    hipLaunchKernelGGL(k_pre,  dim3(129), dim3(256), 0, stream, A, B, Pi, SP, ws);
    hipLaunchKernelGGL(k_mid,  dim3(939), dim3(256), 0, stream, labels, B, ws);
    hipLaunchKernelGGL(k_tree, dim3(16, 4), dim3(1024), 0, stream, ws, out);
}

// Round 3
// 125.981 us; speedup vs baseline: 1.5218x; 1.0526x over previous
//
#include <hip/hip_runtime.h>

// C=8, L=4, M=8192, NGEN=16, DEPTH=6, BATCH=4, N=5461
// Level starts (node space): L0:0 L1:1 L2:5 L3:21 L4:85 L5:341 leaves:1365
// Subtree s (of 16) rooted at L2 node 5+s: L3 21+4s.., L4 85+16s.., L5 341+64s.., leaves local 256s..

// ---- workspace layout (float offsets) ----
#define WS_ASP    0          // 4096  [((i*8+k)*4+j)*16+g]
#define WS_LOGA   4096       // 4096
#define WS_SMPI   8192       // 512
#define WS_LOGPI  8704       // 512
#define WS_LOGSP  9216       // 64
#define WS_PART   9280       // 4096  logsumexp partials
#define WS_SG     13376      // 16384 S accumulators [(b*16+g)*256 + (i*8+k)*4+j]
#define WS_PG     29760      // 128   [pB,pPi] per (b,g)
#define WS_BLEAF  29888      // 524288  [g][p][c]
#define WS_LOGBG  554176     // 2796032 [b][g][node][c]
#define WS_TREE   3350208    // 64*21760 per (b,g)
// tree plane offsets (per (b,g), stride TP_SZ)
#define TP_B5 0
#define TP_Q5 8192
#define TP_B4 16384
#define TP_Q4 18432
#define TP_B3 20480
#define TP_Q3 20992
#define TP_B2 21504
#define TP_Q2 21632
#define TP_SZ 21760
// total 4742848 floats = 19.0 MB

// ---------------- K1: B row logsumexp partials + small-param softmaxes + zero accum ----------------
__global__ void k_pre(const float* __restrict__ A, const float* __restrict__ B,
                      const float* __restrict__ Pi, const float* __restrict__ SP,
                      float* __restrict__ ws) {
    const int t = threadIdx.x;
    if (blockIdx.x < 128) {
        const int c = blockIdx.x >> 4, chunk = blockIdx.x & 15;
        const float* Bp = B + (size_t)c * (8192 * 16) + (size_t)chunk * 8192;
        float mx = -3.4e38f, s = 0.f;
        for (int n = t; n < 8192; n += 256) {
            float v = Bp[n];
            float nm = fmaxf(mx, v);
            s = s * __expf(mx - nm) + __expf(v - nm);
            mx = nm;
        }
        __shared__ float sm[256], ss[256];
        sm[t] = mx; ss[t] = s;
        __syncthreads();
        for (int off = 128; off >= 16; off >>= 1) {
            if (t < off) {
                float m1 = sm[t], m2 = sm[t + off], s1 = ss[t], s2 = ss[t + off];
                float nm = fmaxf(m1, m2);
                sm[t] = nm;
                ss[t] = s1 * __expf(m1 - nm) + s2 * __expf(m2 - nm);
            }
            __syncthreads();
        }
        if (t < 16) {
            float* p = ws + WS_PART + (size_t)(((c * 16 + chunk) * 16 + t) * 2);
            p[0] = sm[t]; p[1] = ss[t];
        }
    } else if (blockIdx.x == 129) {
        for (int i = t; i < 16512; i += 256) ws[WS_SG + i] = 0.f;
    } else {
        __shared__ float s_smSP[64];
        if (t < 16) {
            int g = t;
            float v[4], mx = -3.4e38f;
            for (int j = 0; j < 4; j++) { v[j] = SP[j * 16 + g]; mx = fmaxf(mx, v[j]); }
            float s = 0.f;
            for (int j = 0; j < 4; j++) s += __expf(v[j] - mx);
            float ls = __logf(s);
            for (int j = 0; j < 4; j++) {
                s_smSP[j * 16 + g] = __expf(v[j] - mx) / s;
                ws[WS_LOGSP + j * 16 + g] = v[j] - mx - ls;
            }
        }
        if (t < 64) {
            int g = t & 15, j = t >> 4;
            float v[8], mx = -3.4e38f;
            for (int c = 0; c < 8; c++) { v[c] = Pi[(c * 4 + j) * 16 + g]; mx = fmaxf(mx, v[c]); }
            float s = 0.f;
            for (int c = 0; c < 8; c++) s += __expf(v[c] - mx);
            float ls = __logf(s);
            for (int c = 0; c < 8; c++) {
                int o = (c * 4 + j) * 16 + g;
                ws[WS_SMPI + o] = __expf(v[c] - mx) / s;
                ws[WS_LOGPI + o] = v[c] - mx - ls;
            }
        }
        __syncthreads();
        for (int grp = t; grp < 512; grp += 256) {
            int g = grp & 15, j = (grp >> 4) & 3, k = grp >> 6;
            float v[8], mx = -3.4e38f;
            for (int i = 0; i < 8; i++) { v[i] = A[((i * 8 + k) * 4 + j) * 16 + g]; mx = fmaxf(mx, v[i]); }
            float s = 0.f;
            for (int i = 0; i < 8; i++) s += __expf(v[i] - mx);
            float ls = __logf(s);
            float sp = s_smSP[j * 16 + g];
            for (int i = 0; i < 8; i++) {
                int o = ((i * 8 + k) * 4 + j) * 16 + g;
                ws[WS_ASP + o] = __expf(v[i] - mx) / s * sp;
                ws[WS_LOGA + o] = v[i] - mx - ls;
            }
        }
    }
}

// ---------------- K2: beta_leaf + logB gather ----------------
__global__ void k_mid(const int* __restrict__ labels, const float* __restrict__ B,
                      float* __restrict__ ws) {
    __shared__ float s_ld[128];
    const int t = threadIdx.x;
    if (t < 128) {
        const int c = t >> 4, g = t & 15;
        float mx = -3.4e38f;
        for (int ch = 0; ch < 16; ch++)
            mx = fmaxf(mx, ws[WS_PART + ((c * 16 + ch) * 16 + g) * 2]);
        float s = 0.f;
        for (int ch = 0; ch < 16; ch++) {
            const float* p = ws + WS_PART + (size_t)(((c * 16 + ch) * 16 + g) * 2);
            s += p[1] * __expf(p[0] - mx);
        }
        s_ld[t] = mx + __logf(s);
    }
    __syncthreads();
    if (blockIdx.x < 256) {
        const int id = blockIdx.x * 256 + t;     // 65536 = 4096p * 16g
        const int g = id & 15, p = id >> 4;
        const int pos = p & 3;
        float vals[8], ssum = 0.f;
        #pragma unroll
        for (int c = 0; c < 8; c++) {
            const float smpi = ws[WS_SMPI + (c * 4 + pos) * 16 + g];
            const float v = smpi * __expf(B[((size_t)(c * 8192) + 1365 + p) * 16 + g] - s_ld[c * 16 + g]);
            vals[c] = v; ssum += v;
        }
        const float inv = 1.0f / ssum;
        float* o = ws + WS_BLEAF + (size_t)g * 32768 + (size_t)p * 8;
        *(float4*)o       = make_float4(vals[0] * inv, vals[1] * inv, vals[2] * inv, vals[3] * inv);
        *(float4*)(o + 4) = make_float4(vals[4] * inv, vals[5] * inv, vals[6] * inv, vals[7] * inv);
    } else {
        const int item = (blockIdx.x - 256) * 256 + t;   // 174752 = 4b * 5461node * 8c
        if (item < 174752) {
            const int b = item / 43688;
            const int rem = item - b * 43688;
            const int node = rem >> 3, c = rem & 7;
            const int lv = labels[b * 5461 + node];
            const float* bp = B + ((size_t)(c * 8192) + lv) * 16;
            const float4 q0 = *(const float4*)bp;
            const float4 q1 = *(const float4*)(bp + 4);
            const float4 q2 = *(const float4*)(bp + 8);
            const float4 q3 = *(const float4*)(bp + 12);
            const float vg[16] = {q0.x,q0.y,q0.z,q0.w, q1.x,q1.y,q1.z,q1.w,
                                  q2.x,q2.y,q2.z,q2.w, q3.x,q3.y,q3.z,q3.w};
            float* dst = ws + WS_LOGBG + (size_t)b * (16 * 43688) + (size_t)node * 8 + c;
            #pragma unroll
            for (int g = 0; g < 16; g++)
                dst[(size_t)g * 43688] = vg[g] - s_ld[c * 16 + g];
        }
    }
}

// tt = sum_{j,k} aspU[k*4+j] * bp[j*8+k]
__device__ __forceinline__ float up_tt(const float* bp, const float* aspU) {
    float tt = 0.f;
    #pragma unroll
    for (int j = 0; j < 4; j++) {
        float4 lo = *(const float4*)(bp + j * 8);
        float4 hi = *(const float4*)(bp + j * 8 + 4);
        tt += aspU[0 + j] * lo.x + aspU[4 + j] * lo.y + aspU[8 + j] * lo.z + aspU[12 + j] * lo.w
            + aspU[16 + j] * hi.x + aspU[20 + j] * hi.y + aspU[24 + j] * hi.z + aspU[28 + j] * hi.w;
    }
    return tt;
}

// ---------------- K3: per-(b,g,subtree) up-sweep leaves -> L2 ----------------
__global__ __launch_bounds__(256) void k_up(float* __restrict__ ws) {
    const int x = blockIdx.x;
    const int s = x & 15, g = (x >> 4) & 15, b = x >> 8;
    const int t = threadIdx.x, c8 = t & 7;
    __shared__ __align__(16) float s_blf[2048];
    __shared__ __align__(16) float s_b5[512], s_b4[128], s_b3[32];

    const float* lgb = ws + WS_LOGBG + (size_t)(b * 16 + g) * 43688;
    float* plane     = ws + WS_TREE + (size_t)(b * 16 + g) * TP_SZ;
    const float* blf = ws + WS_BLEAF + (size_t)g * 32768 + (size_t)s * 2048;

    float aspU[32];
    #pragma unroll
    for (int k = 0; k < 8; k++)
        #pragma unroll
        for (int j = 0; j < 4; j++)
            aspU[k * 4 + j] = ws[WS_ASP + ((c8 * 8 + k) * 4 + j) * 16 + g];

    ((float4*)s_blf)[t]       = ((const float4*)blf)[t];
    ((float4*)s_blf)[t + 256] = ((const float4*)blf)[t + 256];
    __syncthreads();

    // L5: 64 nodes
    #pragma unroll
    for (int it = 0; it < 2; ++it) {
        const int p = (it * 256 + t) >> 3;
        const float tt = up_tt(s_blf + p * 32, aspU);
        const float e = __expf(lgb[(341 + s * 64 + p) * 8 + c8]);
        const float bu = tt * e;
        float ssum = bu;
        ssum += __shfl_xor(ssum, 1); ssum += __shfl_xor(ssum, 2); ssum += __shfl_xor(ssum, 4);
        const float beta = bu / ssum;
        s_b5[p * 8 + c8] = beta;
        plane[TP_B5 + (s * 64 + p) * 8 + c8] = beta;
        plane[TP_Q5 + (s * 64 + p) * 8 + c8] = beta / tt;
    }
    __syncthreads();
    // L4: 16 nodes
    if (t < 128) {
        const int p = t >> 3;
        const float tt = up_tt(s_b5 + p * 32, aspU);
        const float e = __expf(lgb[(85 + s * 16 + p) * 8 + c8]);
        const float bu = tt * e;
        float ssum = bu;
        ssum += __shfl_xor(ssum, 1); ssum += __shfl_xor(ssum, 2); ssum += __shfl_xor(ssum, 4);
        const float beta = bu / ssum;
        s_b4[p * 8 + c8] = beta;
        plane[TP_B4 + (s * 16 + p) * 8 + c8] = beta;
        plane[TP_Q4 + (s * 16 + p) * 8 + c8] = beta / tt;
    }
    __syncthreads();
    // L3: 4 nodes
    if (t < 32) {
        const int p = t >> 3;
        const float tt = up_tt(s_b4 + p * 32, aspU);
        const float e = __expf(lgb[(21 + s * 4 + p) * 8 + c8]);
        const float bu = tt * e;
        float ssum = bu;
        ssum += __shfl_xor(ssum, 1); ssum += __shfl_xor(ssum, 2); ssum += __shfl_xor(ssum, 4);
        const float beta = bu / ssum;
        s_b3[p * 8 + c8] = beta;
        plane[TP_B3 + (s * 4 + p) * 8 + c8] = beta;
        plane[TP_Q3 + (s * 4 + p) * 8 + c8] = beta / tt;
    }
    __syncthreads();
    // L2: 1 node
    if (t < 8) {
        const float tt = up_tt(s_b3, aspU);
        const float e = __expf(lgb[(5 + s) * 8 + c8]);
        const float bu = tt * e;
        float ssum = bu;
        ssum += __shfl_xor(ssum, 1); ssum += __shfl_xor(ssum, 2); ssum += __shfl_xor(ssum, 4);
        const float beta = bu / ssum;
        plane[TP_B2 + s * 8 + c8] = beta;
        plane[TP_Q2 + s * 8 + c8] = beta / tt;
    }
}

// u[j] = sum_i aspD[i*4+j]*r8[i]
__device__ __forceinline__ void down_u(const float* r8, const float* aspD, float* u) {
    u[0] = u[1] = u[2] = u[3] = 0.f;
    #pragma unroll
    for (int i = 0; i < 8; i++) {
        u[0] += aspD[i * 4 + 0] * r8[i];
        u[1] += aspD[i * 4 + 1] * r8[i];
        u[2] += aspD[i * 4 + 2] * r8[i];
        u[3] += aspD[i * 4 + 3] * r8[i];
    }
}

// ---------------- K4: per-(b,g,subtree) middle + down-sweep ----------------
__global__ __launch_bounds__(256) void k_down(float* __restrict__ ws) {
    const int x = blockIdx.x;
    const int s = x & 15, g = (x >> 4) & 15, b = x >> 8;
    const int t = threadIdx.x, c8 = t & 7, lane = t & 63, wv = t >> 6;

    __shared__ __align__(16) float s_blf[2048];
    __shared__ __align__(16) float s_b5[512], s_q5[512], s_r5[512];
    __shared__ __align__(16) float s_b4[128], s_q4[128], s_r4[128];
    __shared__ __align__(16) float s_b3[512];   // ALL 64 L3 nodes
    __shared__ __align__(16) float s_q3[32], s_r3[32];
    __shared__ __align__(16) float s_b2[128], s_q2[128], s_r2[128];
    __shared__ float s_b1[32], s_q1[32], s_r1[32];
    __shared__ float s_b0[8], s_q0[8];
    __shared__ float s_asp[256];
    __shared__ __align__(16) float s_stage[1024];
    __shared__ float s_scal[8];

    const float* lgb   = ws + WS_LOGBG + (size_t)(b * 16 + g) * 43688;
    const float* plane = ws + WS_TREE + (size_t)(b * 16 + g) * TP_SZ;
    float* Sg = ws + WS_SG + (size_t)(b * 16 + g) * 256;
    float* Pg = ws + WS_PG + (size_t)(b * 16 + g) * 2;

    s_asp[t] = ws[WS_ASP + t * 16 + g];
    {
        const float4* pb = (const float4*)(ws + WS_BLEAF + (size_t)g * 32768 + (size_t)s * 2048);
        ((float4*)s_blf)[t] = pb[t];
        ((float4*)s_blf)[t + 256] = pb[t + 256];
    }
    if (t < 128) {
        ((float4*)s_b5)[t] = ((const float4*)(plane + TP_B5 + s * 512))[t];
        ((float4*)s_q5)[t] = ((const float4*)(plane + TP_Q5 + s * 512))[t];
        ((float4*)s_b3)[t] = ((const float4*)(plane + TP_B3))[t];
    }
    if (t < 32) {
        ((float4*)s_b4)[t] = ((const float4*)(plane + TP_B4 + s * 128))[t];
        ((float4*)s_q4)[t] = ((const float4*)(plane + TP_Q4 + s * 128))[t];
        ((float4*)s_b2)[t] = ((const float4*)(plane + TP_B2))[t];
        ((float4*)s_q2)[t] = ((const float4*)(plane + TP_Q2))[t];
    }
    if (t < 8) ((float4*)s_q3)[t] = ((const float4*)(plane + TP_Q3 + s * 32))[t];
    __syncthreads();

    float aspD[32];
    #pragma unroll
    for (int i = 0; i < 8; i++)
        #pragma unroll
        for (int j = 0; j < 4; j++)
            aspD[i * 4 + j] = s_asp[(i * 8 + c8) * 4 + j];
    float lpi[4];
    #pragma unroll
    for (int j = 0; j < 4; j++) lpi[j] = ws[WS_LOGPI + (c8 * 4 + j) * 16 + g];

    // ---- middle up (replicated per subtree; trivial) ----
    if (t < 32) {
        const int p = t >> 3;
        float aspU[32];
        #pragma unroll
        for (int k = 0; k < 8; k++)
            #pragma unroll
            for (int j = 0; j < 4; j++) aspU[k * 4 + j] = s_asp[(c8 * 8 + k) * 4 + j];
        const float tt = up_tt(s_b2 + p * 32, aspU);
        const float e = __expf(lgb[(1 + p) * 8 + c8]);
        const float bu = tt * e;
        float ssum = bu;
        ssum += __shfl_xor(ssum, 1); ssum += __shfl_xor(ssum, 2); ssum += __shfl_xor(ssum, 4);
        s_b1[p * 8 + c8] = bu / ssum;
        s_q1[p * 8 + c8] = (bu / ssum) / tt;
    }
    __syncthreads();
    if (t < 8) {
        float aspU[32];
        #pragma unroll
        for (int k = 0; k < 8; k++)
            #pragma unroll
            for (int j = 0; j < 4; j++) aspU[k * 4 + j] = s_asp[(c8 * 8 + k) * 4 + j];
        const float tt = up_tt(s_b1, aspU);
        const float e = __expf(lgb[c8]);
        const float bu = tt * e;
        float ssum = bu;
        ssum += __shfl_xor(ssum, 1); ssum += __shfl_xor(ssum, 2); ssum += __shfl_xor(ssum, 4);
        s_b0[c8] = bu / ssum;
        s_q0[c8] = (bu / ssum) / tt;
    }
    __syncthreads();

    float pB = 0.f, pPi = 0.f;
    float Sacc[32];
    #pragma unroll
    for (int z = 0; z < 32; z++) Sacc[z] = 0.f;

    // ---- d=0 ----
    if (t < 8) {
        float r8[8], u[4];
        #pragma unroll
        for (int i = 0; i < 8; i++) r8[i] = s_q0[i];
        down_u(r8, aspD, u);
        #pragma unroll
        for (int j = 0; j < 4; j++) s_r1[j * 8 + c8] = s_q1[j * 8 + c8] * u[j];
        if (s == 0) {
            pB += s_b0[c8] * lgb[c8];
            #pragma unroll
            for (int j = 0; j < 4; j++) {
                const float bc = s_b1[j * 8 + c8];
                pB += bc * u[j] * lgb[(1 + j) * 8 + c8];
                #pragma unroll
                for (int i = 0; i < 8; i++) Sacc[i * 4 + j] += r8[i] * bc;
            }
        }
    }
    __syncthreads();
    // ---- d=1 ----
    if (t < 32) {
        const int p = t >> 3;
        float r8[8], u[4];
        #pragma unroll
        for (int i = 0; i < 8; i++) r8[i] = s_r1[p * 8 + i];
        down_u(r8, aspD, u);
        #pragma unroll
        for (int j = 0; j < 4; j++) {
            const int ch = 4 * p + j;
            s_r2[ch * 8 + c8] = s_q2[ch * 8 + c8] * u[j];
            if (s == 0) {
                const float bc = s_b2[ch * 8 + c8];
                pB += bc * u[j] * lgb[(5 + ch) * 8 + c8];
                #pragma unroll
                for (int i = 0; i < 8; i++) Sacc[i * 4 + j] += r8[i] * bc;
            }
        }
    }
    __syncthreads();
    // ---- d=2 ----
    if (t < 128) {
        const int p = t >> 3;  // L2 node 0..15
        float r8[8], u[4];
        #pragma unroll
        for (int i = 0; i < 8; i++) r8[i] = s_r2[p * 8 + i];
        down_u(r8, aspD, u);
        #pragma unroll
        for (int j = 0; j < 4; j++) {
            const int ch = 4 * p + j;  // L3 global 0..63
            if (p == s) s_r3[j * 8 + c8] = s_q3[j * 8 + c8] * u[j];
            if (s == 0) {
                const float bc = s_b3[ch * 8 + c8];
                pB += bc * u[j] * lgb[(21 + ch) * 8 + c8];
                #pragma unroll
                for (int i = 0; i < 8; i++) Sacc[i * 4 + j] += r8[i] * bc;
            }
        }
    }
    __syncthreads();
    // ---- d=3 ----
    if (t < 32) {
        const int p = t >> 3;  // own L3 local 0..3
        float r8[8], u[4];
        #pragma unroll
        for (int i = 0; i < 8; i++) r8[i] = s_r3[p * 8 + i];
        down_u(r8, aspD, u);
        #pragma unroll
        for (int j = 0; j < 4; j++) {
            const int ch = 4 * p + j;  // L4 local 0..15
            const float bc = s_b4[ch * 8 + c8];
            pB += bc * u[j] * lgb[(85 + s * 16 + ch) * 8 + c8];
            s_r4[ch * 8 + c8] = s_q4[ch * 8 + c8] * u[j];
            #pragma unroll
            for (int i = 0; i < 8; i++) Sacc[i * 4 + j] += r8[i] * bc;
        }
    }
    __syncthreads();
    // ---- d=4 ----
    if (t < 128) {
        const int p = t >> 3;  // L4 local 0..15
        float r8[8], u[4];
        #pragma unroll
        for (int i = 0; i < 8; i++) r8[i] = s_r4[p * 8 + i];
        down_u(r8, aspD, u);
        #pragma unroll
        for (int j = 0; j < 4; j++) {
            const int ch = 4 * p + j;  // L5 local 0..63
            const float bc = s_b5[ch * 8 + c8];
            pB += bc * u[j] * lgb[(341 + s * 64 + ch) * 8 + c8];
            s_r5[ch * 8 + c8] = s_q5[ch * 8 + c8] * u[j];
            #pragma unroll
            for (int i = 0; i < 8; i++) Sacc[i * 4 + j] += r8[i] * bc;
        }
    }
    __syncthreads();
    // ---- d=5 (leaves) ----
    #pragma unroll
    for (int it = 0; it < 2; ++it) {
        const int p = (it * 256 + t) >> 3;  // L5 local 0..63
        float r8[8], u[4];
        #pragma unroll
        for (int i = 0; i < 8; i++) r8[i] = s_r5[p * 8 + i];
        down_u(r8, aspD, u);
        #pragma unroll
        for (int j = 0; j < 4; j++) {
            const int q = 4 * p + j;  // leaf local 0..255
            const float bc = s_blf[q * 8 + c8];
            const float e6 = bc * u[j];
            pB += e6 * lgb[(1365 + s * 256 + q) * 8 + c8];
            pPi += e6 * lpi[j];
            #pragma unroll
            for (int i = 0; i < 8; i++) Sacc[i * 4 + j] += r8[i] * bc;
        }
    }

    // ---- epilogue: block-reduce, atomic into per-(b,g) accumulators ----
    #pragma unroll
    for (int z = 0; z < 32; z++) {
        float v = Sacc[z];
        v += __shfl_xor(v, 8);
        v += __shfl_xor(v, 16);
        v += __shfl_xor(v, 32);
        Sacc[z] = v;
    }
    #pragma unroll
    for (int m = 1; m < 64; m <<= 1) { pB += __shfl_xor(pB, m); pPi += __shfl_xor(pPi, m); }
    if (lane < 8) {
        #pragma unroll
        for (int z = 0; z < 32; z++)  // i=z>>2, j=z&3, k=lane
            s_stage[wv * 256 + ((z >> 2) * 8 + lane) * 4 + (z & 3)] = Sacc[z];
    }
    if (lane == 0) { s_scal[wv] = pB; s_scal[4 + wv] = pPi; }
    __syncthreads();
    {
        const float TS = s_stage[t] + s_stage[256 + t] + s_stage[512 + t] + s_stage[768 + t];
        atomicAdd(&Sg[t], TS);
    }
    if (t == 0) atomicAdd(&Pg[0], s_scal[0] + s_scal[1] + s_scal[2] + s_scal[3]);
    if (t == 1) atomicAdd(&Pg[1], s_scal[4] + s_scal[5] + s_scal[6] + s_scal[7]);
}

// ---------------- K5: final combine ----------------
__global__ void k_out(const float* __restrict__ ws, float* __restrict__ out) {
    const int x = blockIdx.x;
    const int g = x & 15, b = x >> 4;
    const int t = threadIdx.x;
    __shared__ float s_Alh[4];
    if (t < 4) s_Alh[t] = 0.f;
    __syncthreads();
    const float* Sg = ws + WS_SG + (size_t)(b * 16 + g) * 256;
    const float* Pg = ws + WS_PG + (size_t)(b * 16 + g) * 2;
    const float val = ws[WS_ASP + t * 16 + g] * Sg[t];
    atomicAdd(&s_Alh[t & 3], val * ws[WS_LOGA + t * 16 + g]);
    __syncthreads();
    out[(size_t)b * 4096 + t * 16 + g] =
        -(s_Alh[t & 3] + Pg[0] + Pg[1] + val * ws[WS_LOGSP + (t & 3) * 16 + g]);
}

extern "C" void kernel_launch(void* const* d_in, const int* in_sizes, int n_in,
                              void* d_out, int out_size, void* d_ws, size_t ws_size,
                              hipStream_t stream) {
    (void)in_sizes; (void)n_in; (void)out_size; (void)ws_size;
    const int* labels = (const int*)d_in[0];
    const float* A  = (const float*)d_in[1];
    const float* B  = (const float*)d_in[2];
    const float* Pi = (const float*)d_in[3];
    const float* SP = (const float*)d_in[4];
    float* ws = (float*)d_ws;
    float* out = (float*)d_out;

    hipLaunchKernelGGL(k_pre,  dim3(130), dim3(256), 0, stream, A, B, Pi, SP, ws);
    hipLaunchKernelGGL(k_mid,  dim3(939), dim3(256), 0, stream, labels, B, ws);
    hipLaunchKernelGGL(k_up,   dim3(1024), dim3(256), 0, stream, ws);
    hipLaunchKernelGGL(k_down, dim3(1024), dim3(256), 0, stream, ws);
    hipLaunchKernelGGL(k_out,  dim3(64), dim3(256), 0, stream, ws, out);
}